// Round 3
// 744.539 us; speedup vs baseline: 1.0512x; 1.0512x over previous
//
#include <hip/hip_runtime.h>
#include <math.h>

#define NUM_ROIS 32
#define REG_PER_ROI 50   // 1 + 4 + 9 + 36
#define FH 96
#define FW 96
#define FC 512
#define FC4 (FC / 4)     // 128 float4 per pixel
#define PIXB (FC * 4)    // 2048 bytes per pixel
#define FB 16
#define NREG (NUM_ROIS * REG_PER_ROI)   // 1600
#define RPB 49           // regions computed per roi by kernel1 (s=1..49)

// Kernel 1: one block per (bin s=1..49, batch). 128 threads; thread t owns
// channels [4t,4t+4) as one float4. Flat 1D pixel walk, 16 pixels per group.
//
// R6: R0's verified drain-to-zero structure, depth 8 -> 16.
//  - Addressing is now a SCALAR cursor: x,y,n and bin bounds are
//    block-uniform, so the flat pixel walk (incl. row wrap and the tail
//    clamp-to-last-pixel) is pure SALU; per slot only one v_add folds in the
//    per-thread channel offset. This frees the VGPRs/VALU that 16-deep would
//    otherwise cost.
//  - Loads use SGPR-base + 32-bit voffset (1 VGPR per address, not a pair).
//  - Two 8-load asm blocks (30-operand limit); the second ends with
//    s_waitcnt vmcnt(0), then sched_barrier(0) pins all 16 consumers below
//    the wait (rule #18: "memory" clobber does not order register-only VALU).
//    vmcnt(0) is immune to compiler-vmem miscounts. No tied asm operands.
__global__ __launch_bounds__(128)
void roi_pool_levels(const float* __restrict__ fm,
                     const int* __restrict__ rois,
                     float* __restrict__ out)
{
    const int r = blockIdx.x;            // 0..(32*49-1)
    const int b = blockIdx.y;            // 0..15

    const int roi = r / RPB;
    const int s   = 1 + (r % RPB);       // skip s==0 (derived by kernel 2)

    int p, base;
    if (s < 5)       { p = 2; base = 1; }
    else if (s < 14) { p = 3; base = 5; }
    else             { p = 6; base = 14; }
    const int local = s - base;
    const int ix = local / p;
    const int jy = local % p;

    const int rx = __builtin_amdgcn_readfirstlane(rois[roi * 4 + 0]);
    const int ry = __builtin_amdgcn_readfirstlane(rois[roi * 4 + 1]);
    const int rw = __builtin_amdgcn_readfirstlane(rois[roi * 4 + 2]);
    const int rh = __builtin_amdgcn_readfirstlane(rois[roi * 4 + 3]);

    // Reference's axis swap replicated: cl=h/p drives X, rl=w/p drives Y.
    // Python round() == rint (round-half-even) on doubles.
    const double cl = (double)rh / (double)p;
    const double rl = (double)rw / (double)p;
    const double xd = (double)rx;
    const double yd = (double)ry;

    const int x1 = (int)rint(xd + (double)ix * cl);
    const int x2 = (int)rint(xd + (double)ix * cl + cl);
    const int y1 = (int)rint(yd + (double)jy * rl);
    const int y2 = (int)rint(yd + (double)jy * rl + rl);

    const int spanx = x2 - x1;
    const int n = spanx * (y2 - y1);     // >= 1 always

    // Block-uniform byte-offset cursor into this batch's fm slice.
    const float* __restrict__ fmb = fm + (size_t)b * FH * FW * FC;
    const int c4b = threadIdx.x * 16;                   // per-thread channel bytes
    const int rowjump = (FW - spanx) * PIXB;            // wrap: advance to next row
    const int lastoff = ((y2 - 1) * FW + (x2 - 1)) * PIXB;

    int sx = x1;
    int pixoff = (y1 * FW + x1) * PIXB;

    const float4 ninf = make_float4(-INFINITY, -INFINITY, -INFINITY, -INFINITY);
    float4 acc[4] = {ninf, ninf, ninf, ninf};
    float4 v0, v1, v2, v3, v4, v5, v6, v7;
    float4 w0, w1, w2, w3, w4, w5, w6, w7;

#define ISSUE8(d0,d1,d2,d3,d4,d5,d6,d7, o0,o1,o2,o3,o4,o5,o6,o7, TAILW)       \
    asm volatile(                                                             \
        "global_load_dwordx4 %0, %8, %16\n\t"                                 \
        "global_load_dwordx4 %1, %9, %16\n\t"                                 \
        "global_load_dwordx4 %2, %10, %16\n\t"                                \
        "global_load_dwordx4 %3, %11, %16\n\t"                                \
        "global_load_dwordx4 %4, %12, %16\n\t"                                \
        "global_load_dwordx4 %5, %13, %16\n\t"                                \
        "global_load_dwordx4 %6, %14, %16\n\t"                                \
        "global_load_dwordx4 %7, %15, %16" TAILW                              \
        : "=&v"(d0), "=&v"(d1), "=&v"(d2), "=&v"(d3),                         \
          "=&v"(d4), "=&v"(d5), "=&v"(d6), "=&v"(d7)                          \
        : "v"(o0), "v"(o1), "v"(o2), "v"(o3),                                 \
          "v"(o4), "v"(o5), "v"(o6), "v"(o7),                                 \
          "s"(fmb))

#define CONS4(q0,q1,q2,q3)                                                    \
    do {                                                                      \
        acc[0].x = fmaxf(acc[0].x, q0.x); acc[0].y = fmaxf(acc[0].y, q0.y);   \
        acc[0].z = fmaxf(acc[0].z, q0.z); acc[0].w = fmaxf(acc[0].w, q0.w);   \
        acc[1].x = fmaxf(acc[1].x, q1.x); acc[1].y = fmaxf(acc[1].y, q1.y);   \
        acc[1].z = fmaxf(acc[1].z, q1.z); acc[1].w = fmaxf(acc[1].w, q1.w);   \
        acc[2].x = fmaxf(acc[2].x, q2.x); acc[2].y = fmaxf(acc[2].y, q2.y);   \
        acc[2].z = fmaxf(acc[2].z, q2.z); acc[2].w = fmaxf(acc[2].w, q2.w);   \
        acc[3].x = fmaxf(acc[3].x, q3.x); acc[3].y = fmaxf(acc[3].y, q3.y);   \
        acc[3].z = fmaxf(acc[3].z, q3.z); acc[3].w = fmaxf(acc[3].w, q3.w);   \
    } while (0)

    for (int i = 0; i < n; i += 16) {
        // Scalar walk: 16 slot offsets; slots past n-1 clamp to the bin's
        // last pixel (redundant max, L1-hit, never OOB).
        int so[16];
#pragma unroll
        for (int t = 0; t < 16; ++t) {
            so[t] = (i + t < n) ? pixoff : lastoff;
            ++sx; pixoff += PIXB;
            if (sx == x2) { sx = x1; pixoff += rowjump; }
        }
        // Fold in the per-thread channel offset (one v_add each).
        int vo[16];
#pragma unroll
        for (int t = 0; t < 16; ++t) vo[t] = c4b + so[t];

        ISSUE8(v0,v1,v2,v3,v4,v5,v6,v7,
               vo[0],vo[1],vo[2],vo[3],vo[4],vo[5],vo[6],vo[7], );
        ISSUE8(w0,w1,w2,w3,w4,w5,w6,w7,
               vo[8],vo[9],vo[10],vo[11],vo[12],vo[13],vo[14],vo[15],
               "\n\ts_waitcnt vmcnt(0)");
        __builtin_amdgcn_sched_barrier(0);

        CONS4(v0, v1, v2, v3);
        CONS4(v4, v5, v6, v7);
        CONS4(w0, w1, w2, w3);
        CONS4(w4, w5, w6, w7);
    }
#undef ISSUE8
#undef CONS4

    float4 m;
    m.x = fmaxf(fmaxf(acc[0].x, acc[1].x), fmaxf(acc[2].x, acc[3].x));
    m.y = fmaxf(fmaxf(acc[0].y, acc[1].y), fmaxf(acc[2].y, acc[3].y));
    m.z = fmaxf(fmaxf(acc[0].z, acc[1].z), fmaxf(acc[2].z, acc[3].z));
    m.w = fmaxf(fmaxf(acc[0].w, acc[1].w), fmaxf(acc[2].w, acc[3].w));

    float4* out4 = (float4*)out;
    out4[((size_t)b * NREG + roi * REG_PER_ROI + s) * FC4 + (size_t)threadIdx.x] = m;
}

// Kernel 2: s==0 (p=1, whole footprint) == max of the four p=2 bins, which
// tile the footprint EXACTLY (h/2, w/2 exact in binary; shared boundaries are
// the identical double expression rint(x+cl)).
__global__ __launch_bounds__(128)
void roi_pool_level0(float* __restrict__ out)
{
    const int roi = blockIdx.x;
    const int b   = blockIdx.y;
    const int c4  = threadIdx.x;

    float4* out4 = (float4*)out;
    const size_t base = ((size_t)b * NREG + roi * REG_PER_ROI) * FC4 + c4;

    float4 a = out4[base + 1 * FC4];
    float4 c = out4[base + 2 * FC4];
    float4 d = out4[base + 3 * FC4];
    float4 e = out4[base + 4 * FC4];

    float4 m;
    m.x = fmaxf(fmaxf(a.x, c.x), fmaxf(d.x, e.x));
    m.y = fmaxf(fmaxf(a.y, c.y), fmaxf(d.y, e.y));
    m.z = fmaxf(fmaxf(a.z, c.z), fmaxf(d.z, e.z));
    m.w = fmaxf(fmaxf(a.w, c.w), fmaxf(d.w, e.w));

    out4[base] = m;
}

extern "C" void kernel_launch(void* const* d_in, const int* in_sizes, int n_in,
                              void* d_out, int out_size, void* d_ws, size_t ws_size,
                              hipStream_t stream) {
    const float* fm   = (const float*)d_in[0];
    const int*   rois = (const int*)d_in[1];
    float*       out  = (float*)d_out;

    dim3 grid1(NUM_ROIS * RPB, FB);
    roi_pool_levels<<<grid1, dim3(128), 0, stream>>>(fm, rois, out);

    dim3 grid2(NUM_ROIS, FB);
    roi_pool_level0<<<grid2, dim3(128), 0, stream>>>(out);
}

// Round 4
// 586.798 us; speedup vs baseline: 1.3338x; 1.2688x over previous
//
#include <hip/hip_runtime.h>
#include <math.h>

#define NUM_ROIS 32
#define REG_PER_ROI 50   // 1 + 4 + 9 + 36
#define FH 96
#define FW 96
#define FC 512
#define FC4 (FC / 4)     // 128 float4 per pixel
#define PIXB (FC * 4)    // 2048 bytes per pixel
#define FB 16
#define NREG (NUM_ROIS * REG_PER_ROI)   // 1600
#define NB6 36           // p=6 bins per roi

// ---- float atomic max via int min/max (device scope). Slots pre-init to
// -inf. Positive floats order as signed ints; negative floats reverse-order
// as unsigned. Mixed races resolve correctly (signed max sees any negative
// content as smaller; unsigned min sees any positive content as smaller).
__device__ __forceinline__ void atomic_max_f(float* a, float v) {
    if (v >= 0.0f) atomicMax((int*)a, __float_as_int(v));
    else           atomicMin((unsigned int*)a, __float_as_uint(v));
}

__device__ __forceinline__ float4 fmax4(float4 a, float4 b) {
    return make_float4(fmaxf(a.x,b.x), fmaxf(a.y,b.y),
                       fmaxf(a.z,b.z), fmaxf(a.w,b.w));
}

// Kernel 0: init p2 (s=1..4) and p3 (s=5..13) slots to -inf (atomic targets).
__global__ __launch_bounds__(128)
void roi_init_slots(float* __restrict__ out)
{
    const int roi = blockIdx.x, b = blockIdx.y;
    float4* out4 = (float4*)out;
    const size_t base = ((size_t)b*NREG + (size_t)roi*REG_PER_ROI)*FC4 + threadIdx.x;
    const float4 ninf = make_float4(-INFINITY,-INFINITY,-INFINITY,-INFINITY);
#pragma unroll
    for (int s = 1; s <= 13; ++s) out4[base + (size_t)s*FC4] = ninf;
}

// Kernel 1: one block per (p6 bin l6=0..35, roi, batch). Walks its p6 bin's
// footprint ONCE, split into intersection cells (cuts at p2/p3 boundaries and
// at X2/Y2 when the walk is extended over an inter-bin ulp gap). Each cell's
// max -> p6 register accumulator (if inside [X1,X2)x[Y1,Y2)) + atomic-fmax
// into the containing p2 and p3 slots. This removes the 3x footprint re-read
// (R3 post-mortem: service-rate-limited at ~3.5 TB/s; only fewer bytes help).
//
// Exactness: every edge uses the reference's bit-exact rint expressions.
// p2/p3 interior edges are expression-identical from both sides
// (0*cl+cl == 1*cl, 1*cl+cl == 2*cl exactly in FP). p6 bins can gap/overlap
// at ulp ties; each block walks [X1, max(X2, next_x1)) so gap pixels still
// reach p2/p3 (overlap pixels are walked by both blocks; max is idempotent).
__global__ __launch_bounds__(128)
void roi_pool_p6_cells(const float* __restrict__ fm,
                       const int* __restrict__ rois,
                       float* __restrict__ out)
{
    // XCD-chunked swizzle: 1152 blocks.x = 8 XCDs x 144 (exact) -> each XCD
    // gets 4 whole rois' bins per batch (L2 locality; perf-only remap).
    const int d   = blockIdx.x;
    const int wk  = (d & 7) * 144 + (d >> 3);
    const int roi = wk / NB6;
    const int l6  = wk % NB6;
    const int b   = blockIdx.y;

    const int ix = l6 / 6;
    const int jy = l6 % 6;

    const int rx = __builtin_amdgcn_readfirstlane(rois[roi * 4 + 0]);
    const int ry = __builtin_amdgcn_readfirstlane(rois[roi * 4 + 1]);
    const int rw = __builtin_amdgcn_readfirstlane(rois[roi * 4 + 2]);
    const int rh = __builtin_amdgcn_readfirstlane(rois[roi * 4 + 3]);

    // Axis swap replicated from reference: cl=h/p drives X (ix), rl=w/p
    // drives Y (jy). Python round() == rint on doubles.
    const double cl6 = (double)rh / 6.0, rl6 = (double)rw / 6.0;
    const double cl3 = (double)rh / 3.0, rl3 = (double)rw / 3.0;
    const double xd = (double)rx, yd = (double)ry;

    // Own p6 bin bounds (reference expressions).
    const int X1 = (int)rint(xd + (double)ix * cl6);
    const int X2 = (int)rint(xd + (double)ix * cl6 + cl6);
    const int Y1 = (int)rint(yd + (double)jy * rl6);
    const int Y2 = (int)rint(yd + (double)jy * rl6 + rl6);
    // Next bin's start (gap coverage); walk end = max(own end, next start).
    const int XN = (ix < 5) ? (int)rint(xd + (double)(ix + 1) * cl6) : X2;
    const int YN = (jy < 5) ? (int)rint(yd + (double)(jy + 1) * rl6) : Y2;
    const int XE = X2 > XN ? X2 : XN;
    const int YE = Y2 > YN ? Y2 : YN;

    // p2/p3 interior boundaries (expression-identical both sides).
    const int E2x  = (int)rint(xd + (double)rh * 0.5);
    const int E31x = (int)rint(xd + cl3);
    const int E32x = (int)rint(xd + 2.0 * cl3);
    const int E2y  = (int)rint(yd + (double)rw * 0.5);
    const int E31y = (int)rint(yd + rl3);
    const int E32y = (int)rint(yd + 2.0 * rl3);

    // Build per-axis cell edges: {start} + sorted unique interior cuts + {end}.
    int xedg[6], yedg[6];
    int nxc, nyc;
    {
        int cut[4]; int nc = 0;
        auto addc = [&](int c, int lo, int hi) {
            if (c > lo && c < hi) {
                for (int t = 0; t < nc; ++t) if (cut[t] == c) return;
                cut[nc++] = c;
            }
        };
        nc = 0;
        addc(X2, X1, XE); addc(E2x, X1, XE); addc(E31x, X1, XE); addc(E32x, X1, XE);
        for (int a2 = 1; a2 < nc; ++a2) { int k = cut[a2], t = a2;
            while (t > 0 && cut[t-1] > k) { cut[t] = cut[t-1]; --t; } cut[t] = k; }
        xedg[0] = X1; for (int t = 0; t < nc; ++t) xedg[1+t] = cut[t];
        xedg[nc+1] = XE; nxc = nc + 1;

        nc = 0;
        addc(Y2, Y1, YE); addc(E2y, Y1, YE); addc(E31y, Y1, YE); addc(E32y, Y1, YE);
        for (int a2 = 1; a2 < nc; ++a2) { int k = cut[a2], t = a2;
            while (t > 0 && cut[t-1] > k) { cut[t] = cut[t-1]; --t; } cut[t] = k; }
        yedg[0] = Y1; for (int t = 0; t < nc; ++t) yedg[1+t] = cut[t];
        yedg[nc+1] = YE; nyc = nc + 1;
    }

    const int c4 = threadIdx.x;
    const int c4b = c4 * 16;                 // per-thread channel byte offset
    const float* __restrict__ fmb = fm + (size_t)b * FH * FW * FC;
    const float4 ninf = make_float4(-INFINITY, -INFINITY, -INFINITY, -INFINITY);

#define ISSUE8(d0,d1,d2,d3,d4,d5,d6,d7, o0,o1,o2,o3,o4,o5,o6,o7, TAILW)       \
    asm volatile(                                                             \
        "global_load_dwordx4 %0, %8, %16\n\t"                                 \
        "global_load_dwordx4 %1, %9, %16\n\t"                                 \
        "global_load_dwordx4 %2, %10, %16\n\t"                                \
        "global_load_dwordx4 %3, %11, %16\n\t"                                \
        "global_load_dwordx4 %4, %12, %16\n\t"                                \
        "global_load_dwordx4 %5, %13, %16\n\t"                                \
        "global_load_dwordx4 %6, %14, %16\n\t"                                \
        "global_load_dwordx4 %7, %15, %16" TAILW                              \
        : "=&v"(d0), "=&v"(d1), "=&v"(d2), "=&v"(d3),                         \
          "=&v"(d4), "=&v"(d5), "=&v"(d6), "=&v"(d7)                          \
        : "v"(o0), "v"(o1), "v"(o2), "v"(o3),                                 \
          "v"(o4), "v"(o5), "v"(o6), "v"(o7),                                 \
          "s"(fmb))

#define CONS4(q0,q1,q2,q3)                                                    \
    do {                                                                      \
        a0.x=fmaxf(a0.x,q0.x); a0.y=fmaxf(a0.y,q0.y);                         \
        a0.z=fmaxf(a0.z,q0.z); a0.w=fmaxf(a0.w,q0.w);                         \
        a1.x=fmaxf(a1.x,q1.x); a1.y=fmaxf(a1.y,q1.y);                         \
        a1.z=fmaxf(a1.z,q1.z); a1.w=fmaxf(a1.w,q1.w);                         \
        a2.x=fmaxf(a2.x,q2.x); a2.y=fmaxf(a2.y,q2.y);                         \
        a2.z=fmaxf(a2.z,q2.z); a2.w=fmaxf(a2.w,q2.w);                         \
        a3.x=fmaxf(a3.x,q3.x); a3.y=fmaxf(a3.y,q3.y);                         \
        a3.z=fmaxf(a3.z,q3.z); a3.w=fmaxf(a3.w,q3.w);                         \
    } while (0)

    // Cell pixel walk (R3's verified 16-deep scalar-cursor loop).
    auto cellmax = [&](int ax0, int ax1, int ay0, int ay1) -> float4 {
        const int spanx = ax1 - ax0;
        const int n = spanx * (ay1 - ay0);           // >= 1
        const int rowjump = (FW - spanx) * PIXB;
        const int lastoff = ((ay1 - 1) * FW + (ax1 - 1)) * PIXB;
        int sx = ax0;
        int pixoff = (ay0 * FW + ax0) * PIXB;

        float4 a0 = ninf, a1 = ninf, a2 = ninf, a3 = ninf;
        float4 v0, v1, v2, v3, v4, v5, v6, v7;
        float4 w0, w1, w2, w3, w4, w5, w6, w7;

        for (int i = 0; i < n; i += 16) {
            int so[16];
#pragma unroll
            for (int t = 0; t < 16; ++t) {
                so[t] = (i + t < n) ? pixoff : lastoff;   // tail clamp, L1-hit
                ++sx; pixoff += PIXB;
                if (sx == ax1) { sx = ax0; pixoff += rowjump; }
            }
            int vo[16];
#pragma unroll
            for (int t = 0; t < 16; ++t) vo[t] = c4b + so[t];

            ISSUE8(v0,v1,v2,v3,v4,v5,v6,v7,
                   vo[0],vo[1],vo[2],vo[3],vo[4],vo[5],vo[6],vo[7], );
            ISSUE8(w0,w1,w2,w3,w4,w5,w6,w7,
                   vo[8],vo[9],vo[10],vo[11],vo[12],vo[13],vo[14],vo[15],
                   "\n\ts_waitcnt vmcnt(0)");
            __builtin_amdgcn_sched_barrier(0);

            CONS4(v0, v1, v2, v3);
            CONS4(v4, v5, v6, v7);
            CONS4(w0, w1, w2, w3);
            CONS4(w4, w5, w6, w7);
        }
        float4 m;
        m.x = fmaxf(fmaxf(a0.x, a1.x), fmaxf(a2.x, a3.x));
        m.y = fmaxf(fmaxf(a0.y, a1.y), fmaxf(a2.y, a3.y));
        m.z = fmaxf(fmaxf(a0.z, a1.z), fmaxf(a2.z, a3.z));
        m.w = fmaxf(fmaxf(a0.w, a1.w), fmaxf(a2.w, a3.w));
        return m;
    };

    const size_t robase = (size_t)b * NREG + (size_t)roi * REG_PER_ROI;
    float4 accp6 = ninf;

    for (int cxi = 0; cxi < nxc; ++cxi) {
        const int ax0 = xedg[cxi], ax1 = xedg[cxi + 1];
        const bool inx = (ax1 <= X2);               // cell inside own p6 x-range
        const int sx2 = (ax0 >= E2x) ? 2 : 0;
        const int ix3 = (ax0 >= E31x ? 1 : 0) + (ax0 >= E32x ? 1 : 0);
        for (int cyi = 0; cyi < nyc; ++cyi) {
            const int ay0 = yedg[cyi], ay1 = yedg[cyi + 1];
            const float4 mc = cellmax(ax0, ax1, ay0, ay1);

            if (inx && ay1 <= Y2) accp6 = fmax4(accp6, mc);

            const int s2 = 1 + sx2 + (ay0 >= E2y ? 1 : 0);
            const int s3 = 5 + ix3 * 3 + (ay0 >= E31y ? 1 : 0) + (ay0 >= E32y ? 1 : 0);
            float* p2 = out + ((robase + s2) * FC4 + c4) * 4;
            float* p3 = out + ((robase + s3) * FC4 + c4) * 4;
            atomic_max_f(p2 + 0, mc.x); atomic_max_f(p2 + 1, mc.y);
            atomic_max_f(p2 + 2, mc.z); atomic_max_f(p2 + 3, mc.w);
            atomic_max_f(p3 + 0, mc.x); atomic_max_f(p3 + 1, mc.y);
            atomic_max_f(p3 + 2, mc.z); atomic_max_f(p3 + 3, mc.w);
        }
    }
#undef ISSUE8
#undef CONS4

    // Own p6 slot: exclusive writer, direct store.
    float4* out4 = (float4*)out;
    out4[(robase + (14 + l6)) * FC4 + c4] = accp6;
}

// Kernel 2: s==0 (p=1, whole footprint) == max of the four p=2 bins, which
// tile the footprint EXACTLY (h/2, w/2 exact in binary; shared boundaries are
// the identical double expression rint(x+cl)). Runs after kernel 1 (stream
// order), so p2 slots are complete.
__global__ __launch_bounds__(128)
void roi_pool_level0(float* __restrict__ out)
{
    const int roi = blockIdx.x;
    const int b   = blockIdx.y;
    const int c4  = threadIdx.x;

    float4* out4 = (float4*)out;
    const size_t base = ((size_t)b * NREG + (size_t)roi * REG_PER_ROI) * FC4 + c4;

    float4 a = out4[base + 1 * FC4];
    float4 c = out4[base + 2 * FC4];
    float4 d = out4[base + 3 * FC4];
    float4 e = out4[base + 4 * FC4];

    float4 m;
    m.x = fmaxf(fmaxf(a.x, c.x), fmaxf(d.x, e.x));
    m.y = fmaxf(fmaxf(a.y, c.y), fmaxf(d.y, e.y));
    m.z = fmaxf(fmaxf(a.z, c.z), fmaxf(d.z, e.z));
    m.w = fmaxf(fmaxf(a.w, c.w), fmaxf(d.w, e.w));

    out4[base] = m;
}

extern "C" void kernel_launch(void* const* d_in, const int* in_sizes, int n_in,
                              void* d_out, int out_size, void* d_ws, size_t ws_size,
                              hipStream_t stream) {
    const float* fm   = (const float*)d_in[0];
    const int*   rois = (const int*)d_in[1];
    float*       out  = (float*)d_out;

    dim3 grid0(NUM_ROIS, FB);
    roi_init_slots<<<grid0, dim3(128), 0, stream>>>(out);

    dim3 grid1(NUM_ROIS * NB6, FB);
    roi_pool_p6_cells<<<grid1, dim3(128), 0, stream>>>(fm, rois, out);

    dim3 grid2(NUM_ROIS, FB);
    roi_pool_level0<<<grid2, dim3(128), 0, stream>>>(out);
}

// Round 5
// 528.589 us; speedup vs baseline: 1.4807x; 1.1101x over previous
//
#include <hip/hip_runtime.h>
#include <math.h>

#define NUM_ROIS 32
#define REG_PER_ROI 50   // 1 + 4 + 9 + 36
#define FH 96
#define FW 96
#define FC 512
#define FC4 (FC / 4)     // 128 float4 per pixel
#define PIXB (FC * 4)    // 2048 bytes per pixel
#define FB 16
#define NREG (NUM_ROIS * REG_PER_ROI)   // 1600
#define NB3 9            // p=3 bins per roi (one block each)

// ---- float atomic max via int min/max (device scope). Slots pre-init to
// -inf. Positive floats order as signed ints; negative floats reverse-order
// as unsigned. Mixed races resolve correctly. (Verified passing in R4.)
__device__ __forceinline__ void atomic_max_f(float* a, float v) {
    if (v >= 0.0f) atomicMax((int*)a, __float_as_int(v));
    else           atomicMin((unsigned int*)a, __float_as_uint(v));
}

__device__ __forceinline__ float4 fmax4(float4 a, float4 b) {
    return make_float4(fmaxf(a.x,b.x), fmaxf(a.y,b.y),
                       fmaxf(a.z,b.z), fmaxf(a.w,b.w));
}

// Kernel 0: init p2 slots (s=1..4) to -inf (the only atomic targets left).
__global__ __launch_bounds__(128)
void roi_init_slots(float* __restrict__ out)
{
    const int roi = blockIdx.x, b = blockIdx.y;
    float4* out4 = (float4*)out;
    const size_t base = ((size_t)b*NREG + (size_t)roi*REG_PER_ROI)*FC4 + threadIdx.x;
    const float4 ninf = make_float4(-INFINITY,-INFINITY,-INFINITY,-INFINITY);
#pragma unroll
    for (int s = 1; s <= 4; ++s) out4[base + (size_t)s*FC4] = ninf;
}

// Sorted-unique interior cuts -> edge list. Returns cell count (>= 1).
__device__ __forceinline__ int build_edges(int WS, int WE,
                                           const int* cand, int ncand,
                                           int* edg)
{
    int cut[7]; int nc = 0;
    for (int t = 0; t < ncand; ++t) {
        const int c = cand[t];
        if (c > WS && c < WE) {
            bool dup = false;
            for (int u = 0; u < nc; ++u) if (cut[u] == c) dup = true;
            if (!dup) cut[nc++] = c;
        }
    }
    for (int a = 1; a < nc; ++a) { int k = cut[a], t = a;
        while (t > 0 && cut[t-1] > k) { cut[t] = cut[t-1]; --t; } cut[t] = k; }
    edg[0] = WS;
    for (int t = 0; t < nc; ++t) edg[1 + t] = cut[t];
    edg[nc + 1] = WE;
    return nc + 1;
}

// Kernel 1: one block per (p3 bin l3=0..8, roi, batch). The block owns its
// p3 bin AND the 2x2 p6 sub-bins inside it: those 5 outputs are exclusive
// register accumulators with direct stores (NO atomics). Only p2 (whose cut
// crosses p3 bins) stays atomic, aggregated per block into <=4 register
// partials -> ~20x less atomic traffic than R4 (which showed WRITE_SIZE
// 337 MB, ~300 MB of it p2/p3 atomics).
//
// Exactness: every edge uses the reference's bit-exact rint expressions.
// p3/p6 bins can gap/overlap at ulp (double-rounding: fl(fl(x+k*cl)+cl) vs
// fl(x+(k+1)*cl)); handled by (a) walk extent [min(A1,B1a),
// max(A2,B2b,next-start)], (b) cuts at ALL p3/p6/p2 edges, (c) attribution
// strictly by per-cell range comparisons. Gap cells feed only p2; overlap
// cells are walked by both neighbors and feed both owners (max idempotent).
__global__ __launch_bounds__(128)
void roi_pool_p3_cells(const float* __restrict__ fm,
                       const int* __restrict__ rois,
                       float* __restrict__ out)
{
    // XCD-chunked swizzle: 288 blocks.x = 8 XCDs x 36 (exact, bijective).
    const int d   = blockIdx.x;
    const int wk  = (d & 7) * 36 + (d >> 3);
    const int roi = wk / NB3;
    const int l3  = wk % NB3;
    const int b   = blockIdx.y;

    const int i3 = l3 / 3;               // x-direction p3 index (cl = h/p)
    const int j3 = l3 % 3;               // y-direction p3 index (rl = w/p)
    const int kx0 = 2 * i3, ky0 = 2 * j3;

    const int rx = __builtin_amdgcn_readfirstlane(rois[roi * 4 + 0]);
    const int ry = __builtin_amdgcn_readfirstlane(rois[roi * 4 + 1]);
    const int rw = __builtin_amdgcn_readfirstlane(rois[roi * 4 + 2]);
    const int rh = __builtin_amdgcn_readfirstlane(rois[roi * 4 + 3]);

    // Axis swap replicated from reference: cl=h/p drives X, rl=w/p drives Y.
    const double cl3 = (double)rh / 3.0, rl3 = (double)rw / 3.0;
    const double cl6 = (double)rh / 6.0, rl6 = (double)rw / 6.0;
    const double xd = (double)rx, yd = (double)ry;

    // X edges (reference expressions, bit-exact).
    const int A1x  = (int)rint(xd + (double)i3 * cl3);
    const int A2x  = (int)rint(xd + (double)i3 * cl3 + cl3);
    const int B1x0 = (int)rint(xd + (double)kx0 * cl6);
    const int B2x0 = (int)rint(xd + (double)kx0 * cl6 + cl6);
    const int B1x1 = (int)rint(xd + (double)(kx0 + 1) * cl6);
    const int B2x1 = (int)rint(xd + (double)(kx0 + 1) * cl6 + cl6);
    const int E2x  = (int)rint(xd + (double)rh * 0.5);
    int WSx = min(A1x, B1x0);
    int WEx = max(A2x, B2x1);
    if (i3 < 2) {   // extend over any ulp gap to next block's start
        const int A1n = (int)rint(xd + (double)(i3 + 1) * cl3);
        const int B1n = (int)rint(xd + (double)(kx0 + 2) * cl6);
        const int Sn = min(A1n, B1n);
        WEx = max(WEx, Sn);
    }

    // Y edges.
    const int A1y  = (int)rint(yd + (double)j3 * rl3);
    const int A2y  = (int)rint(yd + (double)j3 * rl3 + rl3);
    const int B1y0 = (int)rint(yd + (double)ky0 * rl6);
    const int B2y0 = (int)rint(yd + (double)ky0 * rl6 + rl6);
    const int B1y1 = (int)rint(yd + (double)(ky0 + 1) * rl6);
    const int B2y1 = (int)rint(yd + (double)(ky0 + 1) * rl6 + rl6);
    const int E2y  = (int)rint(yd + (double)rw * 0.5);
    int WSy = min(A1y, B1y0);
    int WEy = max(A2y, B2y1);
    if (j3 < 2) {
        const int A1n = (int)rint(yd + (double)(j3 + 1) * rl3);
        const int B1n = (int)rint(yd + (double)(ky0 + 2) * rl6);
        const int Sn = min(A1n, B1n);
        WEy = max(WEy, Sn);
    }

    int xedg[9], yedg[9];
    int nxc, nyc;
    {
        const int cx[7] = {A1x, A2x, B1x0, B2x0, B1x1, B2x1, E2x};
        nxc = build_edges(WSx, WEx, cx, 7, xedg);
        const int cy[7] = {A1y, A2y, B1y0, B2y0, B1y1, B2y1, E2y};
        nyc = build_edges(WSy, WEy, cy, 7, yedg);
    }

    const int c4 = threadIdx.x;
    const int c4b = c4 * 16;                 // per-thread channel byte offset
    const float* __restrict__ fmb = fm + (size_t)b * FH * FW * FC;
    const float4 ninf = make_float4(-INFINITY, -INFINITY, -INFINITY, -INFINITY);

#define ISSUE8(d0,d1,d2,d3,d4,d5,d6,d7, o0,o1,o2,o3,o4,o5,o6,o7, TAILW)       \
    asm volatile(                                                             \
        "global_load_dwordx4 %0, %8, %16\n\t"                                 \
        "global_load_dwordx4 %1, %9, %16\n\t"                                 \
        "global_load_dwordx4 %2, %10, %16\n\t"                                \
        "global_load_dwordx4 %3, %11, %16\n\t"                                \
        "global_load_dwordx4 %4, %12, %16\n\t"                                \
        "global_load_dwordx4 %5, %13, %16\n\t"                                \
        "global_load_dwordx4 %6, %14, %16\n\t"                                \
        "global_load_dwordx4 %7, %15, %16" TAILW                              \
        : "=&v"(d0), "=&v"(d1), "=&v"(d2), "=&v"(d3),                         \
          "=&v"(d4), "=&v"(d5), "=&v"(d6), "=&v"(d7)                          \
        : "v"(o0), "v"(o1), "v"(o2), "v"(o3),                                 \
          "v"(o4), "v"(o5), "v"(o6), "v"(o7),                                 \
          "s"(fmb))

#define CONS4(q0,q1,q2,q3)                                                    \
    do {                                                                      \
        a0.x=fmaxf(a0.x,q0.x); a0.y=fmaxf(a0.y,q0.y);                         \
        a0.z=fmaxf(a0.z,q0.z); a0.w=fmaxf(a0.w,q0.w);                         \
        a1.x=fmaxf(a1.x,q1.x); a1.y=fmaxf(a1.y,q1.y);                         \
        a1.z=fmaxf(a1.z,q1.z); a1.w=fmaxf(a1.w,q1.w);                         \
        a2.x=fmaxf(a2.x,q2.x); a2.y=fmaxf(a2.y,q2.y);                         \
        a2.z=fmaxf(a2.z,q2.z); a2.w=fmaxf(a2.w,q2.w);                         \
        a3.x=fmaxf(a3.x,q3.x); a3.y=fmaxf(a3.y,q3.y);                         \
        a3.z=fmaxf(a3.z,q3.z); a3.w=fmaxf(a3.w,q3.w);                         \
    } while (0)

    // Cell pixel walk (R3/R4's verified 16-deep scalar-cursor loop).
    auto cellmax = [&](int ax0, int ax1, int ay0, int ay1) -> float4 {
        const int spanx = ax1 - ax0;
        const int n = spanx * (ay1 - ay0);           // >= 1
        const int rowjump = (FW - spanx) * PIXB;
        const int lastoff = ((ay1 - 1) * FW + (ax1 - 1)) * PIXB;
        int sx = ax0;
        int pixoff = (ay0 * FW + ax0) * PIXB;

        float4 a0 = ninf, a1 = ninf, a2 = ninf, a3 = ninf;
        float4 v0, v1, v2, v3, v4, v5, v6, v7;
        float4 w0, w1, w2, w3, w4, w5, w6, w7;

        for (int i = 0; i < n; i += 16) {
            int so[16];
#pragma unroll
            for (int t = 0; t < 16; ++t) {
                so[t] = (i + t < n) ? pixoff : lastoff;   // tail clamp, L1-hit
                ++sx; pixoff += PIXB;
                if (sx == ax1) { sx = ax0; pixoff += rowjump; }
            }
            int vo[16];
#pragma unroll
            for (int t = 0; t < 16; ++t) vo[t] = c4b + so[t];

            ISSUE8(v0,v1,v2,v3,v4,v5,v6,v7,
                   vo[0],vo[1],vo[2],vo[3],vo[4],vo[5],vo[6],vo[7], );
            ISSUE8(w0,w1,w2,w3,w4,w5,w6,w7,
                   vo[8],vo[9],vo[10],vo[11],vo[12],vo[13],vo[14],vo[15],
                   "\n\ts_waitcnt vmcnt(0)");
            __builtin_amdgcn_sched_barrier(0);

            CONS4(v0, v1, v2, v3);
            CONS4(v4, v5, v6, v7);
            CONS4(w0, w1, w2, w3);
            CONS4(w4, w5, w6, w7);
        }
        float4 m;
        m.x = fmaxf(fmaxf(a0.x, a1.x), fmaxf(a2.x, a3.x));
        m.y = fmaxf(fmaxf(a0.y, a1.y), fmaxf(a2.y, a3.y));
        m.z = fmaxf(fmaxf(a0.z, a1.z), fmaxf(a2.z, a3.z));
        m.w = fmaxf(fmaxf(a0.w, a1.w), fmaxf(a2.w, a3.w));
        return m;
    };

    // Accumulators: all named (static indexing only — rule #20).
    float4 a6_00 = ninf, a6_01 = ninf, a6_10 = ninf, a6_11 = ninf;  // p6 2x2
    float4 p3a   = ninf;                                            // p3 own
    float4 p2_00 = ninf, p2_01 = ninf, p2_10 = ninf, p2_11 = ninf;  // p2 agg
    bool t00 = false, t01 = false, t10 = false, t11 = false;

    for (int cxi = 0; cxi < nxc; ++cxi) {
        const int ax0 = xedg[cxi], ax1 = xedg[cxi + 1];
        const bool x60 = (ax0 >= B1x0) && (ax0 < B2x0);
        const bool x61 = (ax0 >= B1x1) && (ax0 < B2x1);
        const bool x3  = (ax0 >= A1x)  && (ax0 < A2x);
        const bool px2 = (ax0 >= E2x);
        for (int cyi = 0; cyi < nyc; ++cyi) {
            const int ay0 = yedg[cyi], ay1 = yedg[cyi + 1];
            const bool y60 = (ay0 >= B1y0) && (ay0 < B2y0);
            const bool y61 = (ay0 >= B1y1) && (ay0 < B2y1);
            const bool y3  = (ay0 >= A1y)  && (ay0 < A2y);
            const bool py2 = (ay0 >= E2y);

            const float4 mc = cellmax(ax0, ax1, ay0, ay1);

            if (x3 && y3)   p3a   = fmax4(p3a,   mc);
            if (x60 && y60) a6_00 = fmax4(a6_00, mc);
            if (x60 && y61) a6_01 = fmax4(a6_01, mc);
            if (x61 && y60) a6_10 = fmax4(a6_10, mc);
            if (x61 && y61) a6_11 = fmax4(a6_11, mc);
            if (!px2 && !py2) { p2_00 = fmax4(p2_00, mc); t00 = true; }
            if (!px2 &&  py2) { p2_01 = fmax4(p2_01, mc); t01 = true; }
            if ( px2 && !py2) { p2_10 = fmax4(p2_10, mc); t10 = true; }
            if ( px2 &&  py2) { p2_11 = fmax4(p2_11, mc); t11 = true; }
        }
    }
#undef ISSUE8
#undef CONS4

    const size_t robase = (size_t)b * NREG + (size_t)roi * REG_PER_ROI;
    float4* out4 = (float4*)out;

    // p6: exclusive writer per sub-bin (slot 14 + gx*6 + gy).
    out4[(robase + 14 + (kx0 + 0) * 6 + (ky0 + 0)) * FC4 + c4] = a6_00;
    out4[(robase + 14 + (kx0 + 0) * 6 + (ky0 + 1)) * FC4 + c4] = a6_01;
    out4[(robase + 14 + (kx0 + 1) * 6 + (ky0 + 0)) * FC4 + c4] = a6_10;
    out4[(robase + 14 + (kx0 + 1) * 6 + (ky0 + 1)) * FC4 + c4] = a6_11;
    // p3: exclusive writer (slot 5 + i3*3 + j3).
    out4[(robase + 5 + i3 * 3 + j3) * FC4 + c4] = p3a;

    // p2: per-block aggregated atomics (typically 1 slot; <=4).
#define AT2(PX, PY, ACC, T)                                                   \
    if (T) {                                                                  \
        float* p = out + ((robase + 1 + (PX) * 2 + (PY)) * FC4 + c4) * 4;     \
        atomic_max_f(p + 0, ACC.x); atomic_max_f(p + 1, ACC.y);               \
        atomic_max_f(p + 2, ACC.z); atomic_max_f(p + 3, ACC.w);               \
    }
    AT2(0, 0, p2_00, t00)
    AT2(0, 1, p2_01, t01)
    AT2(1, 0, p2_10, t10)
    AT2(1, 1, p2_11, t11)
#undef AT2
}

// Kernel 2: s==0 (p=1, whole footprint) == max of the four p=2 bins, which
// tile the footprint EXACTLY (h/2, w/2 exact in binary; shared boundaries
// are the identical double expression). Runs after kernel 1 (stream order).
__global__ __launch_bounds__(128)
void roi_pool_level0(float* __restrict__ out)
{
    const int roi = blockIdx.x;
    const int b   = blockIdx.y;
    const int c4  = threadIdx.x;

    float4* out4 = (float4*)out;
    const size_t base = ((size_t)b * NREG + (size_t)roi * REG_PER_ROI) * FC4 + c4;

    float4 a = out4[base + 1 * FC4];
    float4 c = out4[base + 2 * FC4];
    float4 d = out4[base + 3 * FC4];
    float4 e = out4[base + 4 * FC4];

    float4 m;
    m.x = fmaxf(fmaxf(a.x, c.x), fmaxf(d.x, e.x));
    m.y = fmaxf(fmaxf(a.y, c.y), fmaxf(d.y, e.y));
    m.z = fmaxf(fmaxf(a.z, c.z), fmaxf(d.z, e.z));
    m.w = fmaxf(fmaxf(a.w, c.w), fmaxf(d.w, e.w));

    out4[base] = m;
}

extern "C" void kernel_launch(void* const* d_in, const int* in_sizes, int n_in,
                              void* d_out, int out_size, void* d_ws, size_t ws_size,
                              hipStream_t stream) {
    const float* fm   = (const float*)d_in[0];
    const int*   rois = (const int*)d_in[1];
    float*       out  = (float*)d_out;

    dim3 grid0(NUM_ROIS, FB);
    roi_init_slots<<<grid0, dim3(128), 0, stream>>>(out);

    dim3 grid1(NUM_ROIS * NB3, FB);
    roi_pool_p3_cells<<<grid1, dim3(128), 0, stream>>>(fm, rois, out);

    dim3 grid2(NUM_ROIS, FB);
    roi_pool_level0<<<grid2, dim3(128), 0, stream>>>(out);
}

// Round 6
// 526.889 us; speedup vs baseline: 1.4855x; 1.0032x over previous
//
#include <hip/hip_runtime.h>
#include <math.h>

#define NUM_ROIS 32
#define REG_PER_ROI 50   // 1 + 4 + 9 + 36
#define FH 96
#define FW 96
#define FC 512
#define FC4 (FC / 4)     // 128 float4 per pixel
#define PIXB (FC * 4)    // 2048 bytes per pixel
#define FB 16
#define NREG (NUM_ROIS * REG_PER_ROI)   // 1600
#define NB3 9            // p=3 bins per roi (one block each)

// ---- float atomic max via int min/max (device scope). Slots pre-init to
// -inf. Verified passing in R4/R5.
__device__ __forceinline__ void atomic_max_f(float* a, float v) {
    if (v >= 0.0f) atomicMax((int*)a, __float_as_int(v));
    else           atomicMin((unsigned int*)a, __float_as_uint(v));
}

__device__ __forceinline__ float4 fmax4(float4 a, float4 b) {
    return make_float4(fmaxf(a.x,b.x), fmaxf(a.y,b.y),
                       fmaxf(a.z,b.z), fmaxf(a.w,b.w));
}

// Kernel 0: init p2 slots (s=1..4) to -inf (the only atomic targets).
__global__ __launch_bounds__(128)
void roi_init_slots(float* __restrict__ out)
{
    const int roi = blockIdx.x, b = blockIdx.y;
    float4* out4 = (float4*)out;
    const size_t base = ((size_t)b*NREG + (size_t)roi*REG_PER_ROI)*FC4 + threadIdx.x;
    const float4 ninf = make_float4(-INFINITY,-INFINITY,-INFINITY,-INFINITY);
#pragma unroll
    for (int s = 1; s <= 4; ++s) out4[base + (size_t)s*FC4] = ninf;
}

// Sorted-unique interior cuts -> edge list. Returns cell count (>= 1).
__device__ __forceinline__ int build_edges(int WS, int WE,
                                           const int* cand, int ncand,
                                           int* edg)
{
    int cut[7]; int nc = 0;
    for (int t = 0; t < ncand; ++t) {
        const int c = cand[t];
        if (c > WS && c < WE) {
            bool dup = false;
            for (int u = 0; u < nc; ++u) if (cut[u] == c) dup = true;
            if (!dup) cut[nc++] = c;
        }
    }
    for (int a = 1; a < nc; ++a) { int k = cut[a], t = a;
        while (t > 0 && cut[t-1] > k) { cut[t] = cut[t-1]; --t; } cut[t] = k; }
    edg[0] = WS;
    for (int t = 0; t < nc; ++t) edg[1 + t] = cut[t];
    edg[nc + 1] = WE;
    return nc + 1;
}

// Kernel 1: one block per (p3 bin l3=0..8, roi, batch); 512 threads = 4
// pixel-groups x 128 channel-threads. R5 post-mortem: occupancy 23%, avg
// block lifetime ~46us vs ~9us of work -> imbalance/straggler tail (p3 bins
// span ~7..450 px) starves the memory system (HBM pinned ~3.2 TB/s for 4
// rounds). R6: same cell/ownership machinery, but 4 groups attack each
// cell's pixels interleaved at 16-px granularity -> block lifetime /4.
// Per-group register partials combine via a 6KB LDS reduction at block end;
// group 0 does the exclusive stores (p3, p6) and aggregated p2 atomics.
__global__ __launch_bounds__(512)
void roi_pool_p3_cells(const float* __restrict__ fm,
                       const int* __restrict__ rois,
                       float* __restrict__ out)
{
    // XCD-chunked swizzle: 288 blocks.x = 8 XCDs x 36 (exact, bijective).
    const int d   = blockIdx.x;
    const int wk  = (d & 7) * 36 + (d >> 3);
    const int roi = wk / NB3;
    const int l3  = wk % NB3;
    const int b   = blockIdx.y;

    const int g  = threadIdx.x >> 7;     // pixel group 0..3
    const int c4 = threadIdx.x & 127;    // channel float4 id

    const int i3 = l3 / 3;               // x-direction p3 index (cl = h/p)
    const int j3 = l3 % 3;               // y-direction p3 index (rl = w/p)
    const int kx0 = 2 * i3, ky0 = 2 * j3;

    const int rx = __builtin_amdgcn_readfirstlane(rois[roi * 4 + 0]);
    const int ry = __builtin_amdgcn_readfirstlane(rois[roi * 4 + 1]);
    const int rw = __builtin_amdgcn_readfirstlane(rois[roi * 4 + 2]);
    const int rh = __builtin_amdgcn_readfirstlane(rois[roi * 4 + 3]);

    // Axis swap replicated from reference: cl=h/p drives X, rl=w/p drives Y.
    const double cl3 = (double)rh / 3.0, rl3 = (double)rw / 3.0;
    const double cl6 = (double)rh / 6.0, rl6 = (double)rw / 6.0;
    const double xd = (double)rx, yd = (double)ry;

    // X edges (reference expressions, bit-exact).
    const int A1x  = (int)rint(xd + (double)i3 * cl3);
    const int A2x  = (int)rint(xd + (double)i3 * cl3 + cl3);
    const int B1x0 = (int)rint(xd + (double)kx0 * cl6);
    const int B2x0 = (int)rint(xd + (double)kx0 * cl6 + cl6);
    const int B1x1 = (int)rint(xd + (double)(kx0 + 1) * cl6);
    const int B2x1 = (int)rint(xd + (double)(kx0 + 1) * cl6 + cl6);
    const int E2x  = (int)rint(xd + (double)rh * 0.5);
    int WSx = min(A1x, B1x0);
    int WEx = max(A2x, B2x1);
    if (i3 < 2) {   // extend over any ulp gap to next block's start
        const int A1n = (int)rint(xd + (double)(i3 + 1) * cl3);
        const int B1n = (int)rint(xd + (double)(kx0 + 2) * cl6);
        const int Sn = min(A1n, B1n);
        WEx = max(WEx, Sn);
    }

    // Y edges.
    const int A1y  = (int)rint(yd + (double)j3 * rl3);
    const int A2y  = (int)rint(yd + (double)j3 * rl3 + rl3);
    const int B1y0 = (int)rint(yd + (double)ky0 * rl6);
    const int B2y0 = (int)rint(yd + (double)ky0 * rl6 + rl6);
    const int B1y1 = (int)rint(yd + (double)(ky0 + 1) * rl6);
    const int B2y1 = (int)rint(yd + (double)(ky0 + 1) * rl6 + rl6);
    const int E2y  = (int)rint(yd + (double)rw * 0.5);
    int WSy = min(A1y, B1y0);
    int WEy = max(A2y, B2y1);
    if (j3 < 2) {
        const int A1n = (int)rint(yd + (double)(j3 + 1) * rl3);
        const int B1n = (int)rint(yd + (double)(ky0 + 2) * rl6);
        const int Sn = min(A1n, B1n);
        WEy = max(WEy, Sn);
    }

    int xedg[9], yedg[9];
    int nxc, nyc;
    {
        const int cx[7] = {A1x, A2x, B1x0, B2x0, B1x1, B2x1, E2x};
        nxc = build_edges(WSx, WEx, cx, 7, xedg);
        const int cy[7] = {A1y, A2y, B1y0, B2y0, B1y1, B2y1, E2y};
        nyc = build_edges(WSy, WEy, cy, 7, yedg);
    }

    const int c4b = c4 * 16;                 // per-thread channel byte offset
    const float* __restrict__ fmb = fm + (size_t)b * FH * FW * FC;
    const float4 ninf = make_float4(-INFINITY, -INFINITY, -INFINITY, -INFINITY);

#define ISSUE8(d0,d1,d2,d3,d4,d5,d6,d7, o0,o1,o2,o3,o4,o5,o6,o7, TAILW)       \
    asm volatile(                                                             \
        "global_load_dwordx4 %0, %8, %16\n\t"                                 \
        "global_load_dwordx4 %1, %9, %16\n\t"                                 \
        "global_load_dwordx4 %2, %10, %16\n\t"                                \
        "global_load_dwordx4 %3, %11, %16\n\t"                                \
        "global_load_dwordx4 %4, %12, %16\n\t"                                \
        "global_load_dwordx4 %5, %13, %16\n\t"                                \
        "global_load_dwordx4 %6, %14, %16\n\t"                                \
        "global_load_dwordx4 %7, %15, %16" TAILW                              \
        : "=&v"(d0), "=&v"(d1), "=&v"(d2), "=&v"(d3),                         \
          "=&v"(d4), "=&v"(d5), "=&v"(d6), "=&v"(d7)                          \
        : "v"(o0), "v"(o1), "v"(o2), "v"(o3),                                 \
          "v"(o4), "v"(o5), "v"(o6), "v"(o7),                                 \
          "s"(fmb))

#define CONS4(q0,q1,q2,q3)                                                    \
    do {                                                                      \
        a0.x=fmaxf(a0.x,q0.x); a0.y=fmaxf(a0.y,q0.y);                         \
        a0.z=fmaxf(a0.z,q0.z); a0.w=fmaxf(a0.w,q0.w);                         \
        a1.x=fmaxf(a1.x,q1.x); a1.y=fmaxf(a1.y,q1.y);                         \
        a1.z=fmaxf(a1.z,q1.z); a1.w=fmaxf(a1.w,q1.w);                         \
        a2.x=fmaxf(a2.x,q2.x); a2.y=fmaxf(a2.y,q2.y);                         \
        a2.z=fmaxf(a2.z,q2.z); a2.w=fmaxf(a2.w,q2.w);                         \
        a3.x=fmaxf(a3.x,q3.x); a3.y=fmaxf(a3.y,q3.y);                         \
        a3.z=fmaxf(a3.z,q3.z); a3.w=fmaxf(a3.w,q3.w);                         \
    } while (0)

    // Cell pixel walk. Group g handles pixel blocks [16(g+4k), 16(g+4k)+16):
    // same verified 16-deep pipeline, outer stride 64 px. One int div per
    // 64 px relocates the (row, col) cursor (VALUBusy was 6.8% -- cheap).
    auto cellmax = [&](int ax0, int ax1, int ay0, int ay1) -> float4 {
        const int spanx = ax1 - ax0;
        const int n = spanx * (ay1 - ay0);           // >= 1
        const int rowjump = (FW - spanx) * PIXB;
        const int lastoff = ((ay1 - 1) * FW + (ax1 - 1)) * PIXB;

        float4 a0 = ninf, a1 = ninf, a2 = ninf, a3 = ninf;
        float4 v0, v1, v2, v3, v4, v5, v6, v7;
        float4 w0, w1, w2, w3, w4, w5, w6, w7;

        for (int i = 16 * g; i < n; i += 64) {
            const int sy0 = i / spanx;               // uniform per group
            int sx = ax0 + (i - sy0 * spanx);
            int pixoff = ((ay0 + sy0) * FW + sx) * PIXB;
            int so[16];
#pragma unroll
            for (int t = 0; t < 16; ++t) {
                so[t] = (i + t < n) ? pixoff : lastoff;   // tail clamp (in-cell)
                ++sx; pixoff += PIXB;
                if (sx == ax1) { sx = ax0; pixoff += rowjump; }
            }
            int vo[16];
#pragma unroll
            for (int t = 0; t < 16; ++t) vo[t] = c4b + so[t];

            ISSUE8(v0,v1,v2,v3,v4,v5,v6,v7,
                   vo[0],vo[1],vo[2],vo[3],vo[4],vo[5],vo[6],vo[7], );
            ISSUE8(w0,w1,w2,w3,w4,w5,w6,w7,
                   vo[8],vo[9],vo[10],vo[11],vo[12],vo[13],vo[14],vo[15],
                   "\n\ts_waitcnt vmcnt(0)");
            __builtin_amdgcn_sched_barrier(0);

            CONS4(v0, v1, v2, v3);
            CONS4(v4, v5, v6, v7);
            CONS4(w0, w1, w2, w3);
            CONS4(w4, w5, w6, w7);
        }
        float4 m;
        m.x = fmaxf(fmaxf(a0.x, a1.x), fmaxf(a2.x, a3.x));
        m.y = fmaxf(fmaxf(a0.y, a1.y), fmaxf(a2.y, a3.y));
        m.z = fmaxf(fmaxf(a0.z, a1.z), fmaxf(a2.z, a3.z));
        m.w = fmaxf(fmaxf(a0.w, a1.w), fmaxf(a2.w, a3.w));
        return m;
    };

    // Accumulators: all named (static indexing only — rule #20).
    float4 a6_00 = ninf, a6_01 = ninf, a6_10 = ninf, a6_11 = ninf;  // p6 2x2
    float4 p3a   = ninf;                                            // p3 own
    float4 p2_00 = ninf, p2_01 = ninf, p2_10 = ninf, p2_11 = ninf;  // p2 agg
    bool t00 = false, t01 = false, t10 = false, t11 = false;

    for (int cxi = 0; cxi < nxc; ++cxi) {
        const int ax0 = xedg[cxi], ax1 = xedg[cxi + 1];
        const bool x60 = (ax0 >= B1x0) && (ax0 < B2x0);
        const bool x61 = (ax0 >= B1x1) && (ax0 < B2x1);
        const bool x3  = (ax0 >= A1x)  && (ax0 < A2x);
        const bool px2 = (ax0 >= E2x);
        for (int cyi = 0; cyi < nyc; ++cyi) {
            const int ay0 = yedg[cyi], ay1 = yedg[cyi + 1];
            const bool y60 = (ay0 >= B1y0) && (ay0 < B2y0);
            const bool y61 = (ay0 >= B1y1) && (ay0 < B2y1);
            const bool y3  = (ay0 >= A1y)  && (ay0 < A2y);
            const bool py2 = (ay0 >= E2y);

            const float4 mc = cellmax(ax0, ax1, ay0, ay1);

            if (x3 && y3)   p3a   = fmax4(p3a,   mc);
            if (x60 && y60) a6_00 = fmax4(a6_00, mc);
            if (x60 && y61) a6_01 = fmax4(a6_01, mc);
            if (x61 && y60) a6_10 = fmax4(a6_10, mc);
            if (x61 && y61) a6_11 = fmax4(a6_11, mc);
            if (!px2 && !py2) { p2_00 = fmax4(p2_00, mc); t00 = true; }
            if (!px2 &&  py2) { p2_01 = fmax4(p2_01, mc); t01 = true; }
            if ( px2 && !py2) { p2_10 = fmax4(p2_10, mc); t10 = true; }
            if ( px2 &&  py2) { p2_11 = fmax4(p2_11, mc); t11 = true; }
        }
    }
#undef ISSUE8
#undef CONS4

    // Cross-group combine: 9 slots, sequential LDS rounds (6 KB buffer).
    // Geometry (flags) is block-uniform, so group 0's flags are valid.
    __shared__ float4 red[3][128];
#define BLKRED(ACC)                                                           \
    do {                                                                      \
        __syncthreads();                                                      \
        if (g > 0) red[g - 1][c4] = ACC;                                      \
        __syncthreads();                                                      \
        if (g == 0)                                                           \
            ACC = fmax4(fmax4(red[0][c4], red[1][c4]),                        \
                        fmax4(red[2][c4], ACC));                              \
    } while (0)
    BLKRED(a6_00); BLKRED(a6_01); BLKRED(a6_10); BLKRED(a6_11);
    BLKRED(p3a);
    BLKRED(p2_00); BLKRED(p2_01); BLKRED(p2_10); BLKRED(p2_11);
#undef BLKRED

    if (g != 0) return;

    const size_t robase = (size_t)b * NREG + (size_t)roi * REG_PER_ROI;
    float4* out4 = (float4*)out;

    // p6: exclusive writer per sub-bin (slot 14 + gx*6 + gy).
    out4[(robase + 14 + (kx0 + 0) * 6 + (ky0 + 0)) * FC4 + c4] = a6_00;
    out4[(robase + 14 + (kx0 + 0) * 6 + (ky0 + 1)) * FC4 + c4] = a6_01;
    out4[(robase + 14 + (kx0 + 1) * 6 + (ky0 + 0)) * FC4 + c4] = a6_10;
    out4[(robase + 14 + (kx0 + 1) * 6 + (ky0 + 1)) * FC4 + c4] = a6_11;
    // p3: exclusive writer (slot 5 + i3*3 + j3).
    out4[(robase + 5 + i3 * 3 + j3) * FC4 + c4] = p3a;

    // p2: per-block aggregated atomics (typically 1 slot; <=4).
#define AT2(PX, PY, ACC, T)                                                   \
    if (T) {                                                                  \
        float* p = out + ((robase + 1 + (PX) * 2 + (PY)) * FC4 + c4) * 4;     \
        atomic_max_f(p + 0, ACC.x); atomic_max_f(p + 1, ACC.y);               \
        atomic_max_f(p + 2, ACC.z); atomic_max_f(p + 3, ACC.w);               \
    }
    AT2(0, 0, p2_00, t00)
    AT2(0, 1, p2_01, t01)
    AT2(1, 0, p2_10, t10)
    AT2(1, 1, p2_11, t11)
#undef AT2
}

// Kernel 2: s==0 (p=1, whole footprint) == max of the four p=2 bins, which
// tile the footprint EXACTLY (h/2, w/2 exact in binary; shared boundaries
// are the identical double expression). Runs after kernel 1 (stream order).
__global__ __launch_bounds__(128)
void roi_pool_level0(float* __restrict__ out)
{
    const int roi = blockIdx.x;
    const int b   = blockIdx.y;
    const int c4  = threadIdx.x;

    float4* out4 = (float4*)out;
    const size_t base = ((size_t)b * NREG + (size_t)roi * REG_PER_ROI) * FC4 + c4;

    float4 a = out4[base + 1 * FC4];
    float4 c = out4[base + 2 * FC4];
    float4 d = out4[base + 3 * FC4];
    float4 e = out4[base + 4 * FC4];

    float4 m;
    m.x = fmaxf(fmaxf(a.x, c.x), fmaxf(d.x, e.x));
    m.y = fmaxf(fmaxf(a.y, c.y), fmaxf(d.y, e.y));
    m.z = fmaxf(fmaxf(a.z, c.z), fmaxf(d.z, e.z));
    m.w = fmaxf(fmaxf(a.w, c.w), fmaxf(d.w, e.w));

    out4[base] = m;
}

extern "C" void kernel_launch(void* const* d_in, const int* in_sizes, int n_in,
                              void* d_out, int out_size, void* d_ws, size_t ws_size,
                              hipStream_t stream) {
    const float* fm   = (const float*)d_in[0];
    const int*   rois = (const int*)d_in[1];
    float*       out  = (float*)d_out;

    dim3 grid0(NUM_ROIS, FB);
    roi_init_slots<<<grid0, dim3(128), 0, stream>>>(out);

    dim3 grid1(NUM_ROIS * NB3, FB);
    roi_pool_p3_cells<<<grid1, dim3(512), 0, stream>>>(fm, rois, out);

    dim3 grid2(NUM_ROIS, FB);
    roi_pool_level0<<<grid2, dim3(128), 0, stream>>>(out);
}